// Round 13
// baseline (293.994 us; speedup 1.0000x reference)
//
#include <hip/hip_runtime.h>
#include <stdint.h>

#define TOK 4096
#define CH  1024
#define NH  16
#define HD  64
#define FF  4096

typedef __attribute__((ext_vector_type(8))) short bf16x8;
typedef __attribute__((ext_vector_type(4))) float f32x4;
typedef __attribute__((ext_vector_type(16))) float f32x16;

__device__ __forceinline__ unsigned short f2bf(float f) {
    union { float f; unsigned u; } v; v.f = f;
    unsigned u = v.u;
    u += 0x7fffu + ((u >> 16) & 1u);
    return (unsigned short)(u >> 16);
}

__device__ __forceinline__ float bf2f(unsigned short s) {
    union { unsigned u; float f; } v; v.u = ((unsigned)s) << 16;
    return v.f;
}

__device__ __forceinline__ unsigned cvtpk(float a, float b) {
    unsigned r;
    asm("v_cvt_pk_bf16_f32 %0, %1, %2" : "=v"(r) : "v"(a), "v"(b));
    return r;
}

__device__ __forceinline__ void load_lds16(const void* g, void* l) {
    __builtin_amdgcn_global_load_lds(
        (const __attribute__((address_space(1))) unsigned int*)g,
        (__attribute__((address_space(3))) unsigned int*)l, 16, 0, 0);
}

// counted-vmcnt barrier: N loads may stay in flight
template<int N> __device__ __forceinline__ void wait_vm_lgkm0() {
    if constexpr (N == 0)      asm volatile("s_waitcnt vmcnt(0) lgkmcnt(0)" ::: "memory");
    else if constexpr (N == 4) asm volatile("s_waitcnt vmcnt(4) lgkmcnt(0)" ::: "memory");
    else if constexpr (N == 8) asm volatile("s_waitcnt vmcnt(8) lgkmcnt(0)" ::: "memory");
    __builtin_amdgcn_sched_barrier(0);
    __builtin_amdgcn_s_barrier();
}

__device__ __forceinline__ float gelu_tanh(float u) {
    float z = 0.7978845608028654f * (u + 0.044715f * u * u * u);
    float e = __expf(2.0f * z);
    return 0.5f * u * (1.0f + (1.0f - 2.0f / (e + 1.0f)));
}

// ---- weight transpose+cast: in [K][Nn] f32 -> out [Nn][K] bf16 (vectorized) ----
__global__ __launch_bounds__(256) void wT_kernel(const float* __restrict__ in,
                                                 unsigned short* __restrict__ out,
                                                 int K, int Nn) {
    __shared__ float tile[32][36];
    int k0 = blockIdx.x * 32, n0 = blockIdx.y * 32;
    int t = threadIdx.x;
    int r = t >> 3, c4 = (t & 7) * 4;
    float4 v = *(const float4*)(in + (size_t)(k0 + r) * Nn + n0 + c4);
    *(float4*)&tile[r][c4] = v;
    __syncthreads();
    ushort4 o;
    o.x = f2bf(tile[c4 + 0][r]);
    o.y = f2bf(tile[c4 + 1][r]);
    o.z = f2bf(tile[c4 + 2][r]);
    o.w = f2bf(tile[c4 + 3][r]);
    *(ushort4*)(out + (size_t)(n0 + r) * K + k0 + c4) = o;
}

// ---- rmsnorm: f32 row -> bf16 row ----
__global__ __launch_bounds__(256) void rms_kernel(const float* __restrict__ x,
                                                  const float* __restrict__ g,
                                                  unsigned short* __restrict__ out) {
    int row = blockIdx.x, t = threadIdx.x;
    const float4* xr = (const float4*)(x + (size_t)row * CH);
    float4 v = xr[t];
    float ss = v.x * v.x + v.y * v.y + v.z * v.z + v.w * v.w;
#pragma unroll
    for (int m = 32; m; m >>= 1) ss += __shfl_xor(ss, m, 64);
    __shared__ float wsum[4];
    if ((t & 63) == 0) wsum[t >> 6] = ss;
    __syncthreads();
    float inv = rsqrtf((wsum[0] + wsum[1] + wsum[2] + wsum[3]) * (1.0f / CH) + 1e-6f);
    float4 gv = ((const float4*)g)[t];
    ushort4 o;
    o.x = f2bf(v.x * inv * gv.x);
    o.y = f2bf(v.y * inv * gv.y);
    o.z = f2bf(v.z * inv * gv.z);
    o.w = f2bf(v.w * inv * gv.w);
    ((ushort4*)(out + (size_t)row * CH))[t] = o;
}

// ---- small GEMM (wo/w2): C = A * Bt^T, 64x64 tile, 4 waves ----
// 4-buffer LDS, 2 K-tiles per drain+barrier (round-12 attn pattern).
template<int BM, int BN, int EPI>
__global__ __launch_bounds__(256) void gemm_bt(const unsigned short* __restrict__ A,
                                               const unsigned short* __restrict__ Bt,
                                               void* __restrict__ outp,
                                               const float* __restrict__ resid,
                                               int M, int Nn, int K) {
    __shared__ __align__(16) unsigned short ldsA[4][BM * 32];
    __shared__ __align__(16) unsigned short ldsB[4][BN * 32];
    const int t = threadIdx.x, l = t & 63, w = t >> 6;
    const int nbn = Nn / BN;
    const int bid = blockIdx.x, nwg = gridDim.x, cpx = nwg >> 3;
    const int swz = (bid & 7) * cpx + (bid >> 3);
    const int bm = swz / nbn, bn = swz % nbn;
    const int wr = w >> 1, wc = w & 1;
    constexpr int MF = BM / 32, NF = BN / 32;
    const unsigned short* Ag = A + (size_t)bm * BM * K;
    const unsigned short* Bg = Bt + (size_t)bn * BN * K;

    f32x4 acc[MF][NF];
#pragma unroll
    for (int m = 0; m < MF; m++)
#pragma unroll
        for (int n = 0; n < NF; n++) acc[m][n] = {0.f, 0.f, 0.f, 0.f};

    auto stage = [&](int kt) {
        const int buf = kt & 3;
#pragma unroll
        for (int p = 0; p < BM / 64; p++) {
            int c = t + 256 * p;
            load_lds16(Ag + (size_t)(c >> 2) * K + kt * 32 + (c & 3) * 8, &ldsA[buf][c * 8]);
        }
#pragma unroll
        for (int p = 0; p < BN / 64; p++) {
            int c = t + 256 * p;
            load_lds16(Bg + (size_t)(c >> 2) * K + kt * 32 + (c & 3) * 8, &ldsB[buf][c * 8]);
        }
    };

    auto compute = [&](int kt) {
        const int buf = kt & 3;
        bf16x8 af[MF], bfr[NF];
#pragma unroll
        for (int m = 0; m < MF; m++)
            af[m] = *(const bf16x8*)&ldsA[buf][(wr * (BM / 2) + m * 16 + (l & 15)) * 32 + (l >> 4) * 8];
#pragma unroll
        for (int n = 0; n < NF; n++)
            bfr[n] = *(const bf16x8*)&ldsB[buf][(wc * (BN / 2) + n * 16 + (l & 15)) * 32 + (l >> 4) * 8];
#pragma unroll
        for (int m = 0; m < MF; m++)
#pragma unroll
            for (int n = 0; n < NF; n++)
                acc[m][n] = __builtin_amdgcn_mfma_f32_16x16x32_bf16(af[m], bfr[n], acc[m][n], 0, 0, 0);
    };

    const int nkt = K >> 5;                  // even for all our K
    stage(0); stage(1);
    for (int kt = 0; kt < nkt; kt += 2) {
        wait_vm_lgkm0<0>();                  // tiles kt,kt+1 landed; prior reads drained
        if (kt + 2 < nkt) { stage(kt + 2); stage(kt + 3); }
        compute(kt);
        compute(kt + 1);
    }

    const int r0 = bm * BM + wr * (BM / 2), c0 = bn * BN + wc * (BN / 2);
#pragma unroll
    for (int m = 0; m < MF; m++)
#pragma unroll
        for (int n = 0; n < NF; n++)
#pragma unroll
            for (int r = 0; r < 4; r++) {
                int rr = r0 + m * 16 + (l >> 4) * 4 + r;
                int cc = c0 + n * 16 + (l & 15);
                float v = acc[m][n][r];
                if (EPI == 0) {
                    ((unsigned short*)outp)[(size_t)rr * Nn + cc] = f2bf(v);
                } else if (EPI == 1) {
                    ((unsigned short*)outp)[(size_t)rr * Nn + cc] = f2bf(gelu_tanh(v));
                } else {
                    ((float*)outp)[(size_t)rr * Nn + cc] = resid[(size_t)rr * Nn + cc] + v;
                }
            }
}

// ---- big GEMM (qkv/w1): 256x256 tile, BK=64, 8 waves (2M x 4N), 512 threads ----
template<int EPI>
__global__ __launch_bounds__(512) void gemm256(const unsigned short* __restrict__ A,
                                               const unsigned short* __restrict__ Bt,
                                               void* __restrict__ outp,
                                               unsigned short* __restrict__ vout,
                                               int M, int Nn, int K) {
    __shared__ __align__(16) unsigned short lds[2][4][8192];
    const int t = threadIdx.x, l = t & 63, w = t >> 6;
    const int wr = w >> 2, wc = w & 3;
    const int nbn = Nn >> 8;
    const int bid = blockIdx.x, nwg = gridDim.x, cpx = nwg >> 3;
    const int swz = (bid & 7) * cpx + (bid >> 3);
    const int bm = swz / nbn, bn = swz % nbn;

    const int lbase = (((l & 15) * 64 + (l >> 4) * 16)) ^ (((l >> 3) & 1) << 5);

    int srow[2], scol[2];
#pragma unroll
    for (int L = 0; L < 2; L++) {
        int g = t + L * 512;
        int s = g >> 6;
        int wb = ((g & 63) * 16) ^ (((g >> 5) & 1) << 5);
        srow[L] = (s >> 1) * 16 + (wb >> 6);
        scol[L] = (s & 1) * 32 + ((wb & 63) >> 1);
    }

    const unsigned short* Asrc = A + (size_t)(bm * 256) * K;
    const unsigned short* Bsrc = Bt + (size_t)(bn * 256) * K;

    auto stage_half = [&](int j) {
        const int kt = j >> 2, slot = j & 3;
        const unsigned short* base = (slot < 2 ? Asrc : Bsrc) + (size_t)((slot & 1) * 128) * K;
#pragma unroll
        for (int L = 0; L < 2; L++)
            load_lds16(base + (size_t)srow[L] * K + kt * 64 + scol[L],
                       &lds[kt & 1][slot][(t + L * 512) * 8]);
    };

    f32x4 acc[8][4];
#pragma unroll
    for (int m = 0; m < 8; m++)
#pragma unroll
        for (int n = 0; n < 4; n++) acc[m][n] = {0.f, 0.f, 0.f, 0.f};

    const int nkt = K >> 6;
    stage_half(0); stage_half(1); stage_half(2); stage_half(3);

    for (int kt = 0; kt < nkt; kt++) {
        wait_vm_lgkm0<0>();
        const char* Abase = (const char*)&lds[kt & 1][wr][0];
        const char* Bbase = (const char*)&lds[kt & 1][2 + (wc >> 1)][0];
        bf16x8 bfr[4][2];
#pragma unroll
        for (int q = 0; q < 4; q++) {
            if (q == 0) {
#pragma unroll
                for (int n = 0; n < 4; n++)
#pragma unroll
                    for (int ks = 0; ks < 2; ks++)
                        bfr[n][ks] = *(const bf16x8*)(Bbase + ((((wc & 1) * 4 + n) * 2 + ks) * 1024 + lbase));
            }
            bf16x8 af[2][2];
#pragma unroll
            for (int mi = 0; mi < 2; mi++)
#pragma unroll
                for (int ks = 0; ks < 2; ks++)
                    af[mi][ks] = *(const bf16x8*)(Abase + (((q * 2 + mi) * 2 + ks) * 1024 + lbase));
            if (kt + 1 < nkt) stage_half((kt + 1) * 4 + q);
            __builtin_amdgcn_s_barrier();
            __builtin_amdgcn_s_setprio(1);
#pragma unroll
            for (int mi = 0; mi < 2; mi++)
#pragma unroll
                for (int n = 0; n < 4; n++) {
                    acc[q * 2 + mi][n] = __builtin_amdgcn_mfma_f32_16x16x32_bf16(af[mi][0], bfr[n][0], acc[q * 2 + mi][n], 0, 0, 0);
                    acc[q * 2 + mi][n] = __builtin_amdgcn_mfma_f32_16x16x32_bf16(af[mi][1], bfr[n][1], acc[q * 2 + mi][n], 0, 0, 0);
                }
            __builtin_amdgcn_s_setprio(0);
            __builtin_amdgcn_s_barrier();
        }
    }

    const int r0 = bm * 256 + wr * 128, c0 = bn * 256 + wc * 64;
    const bool vpart = (EPI == 3) && (c0 >= 2048);
#pragma unroll
    for (int m = 0; m < 8; m++)
#pragma unroll
        for (int n = 0; n < 4; n++) {
            if (vpart) {
                int cc = c0 + n * 16 + (l & 15);
                int rrb = r0 + m * 16 + (l >> 4) * 4;
                ushort4 pk;
                pk.x = f2bf(acc[m][n][0]);
                pk.y = f2bf(acc[m][n][1]);
                pk.z = f2bf(acc[m][n][2]);
                pk.w = f2bf(acc[m][n][3]);
                *(ushort4*)(vout + (size_t)(cc - 2048) * 4096 + rrb) = pk;
            } else {
#pragma unroll
                for (int r = 0; r < 4; r++) {
                    int rr = r0 + m * 16 + (l >> 4) * 4 + r;
                    int cc = c0 + n * 16 + (l & 15);
                    float v = acc[m][n][r];
                    if (EPI == 1) {
                        ((unsigned short*)outp)[(size_t)rr * Nn + cc] = f2bf(gelu_tanh(v));
                    } else {
                        float sc = (cc < 1024) ? 0.180336880f : 1.0f;   // 0.125*log2(e)
                        ((unsigned short*)outp)[(size_t)rr * Nn + cc] = f2bf(v * sc);
                    }
                }
            }
        }
}

// ---- flash attention, split-KV (blockIdx.z picks half), un-normalized bf16 partials ----
// Partial z=0 -> dead v-slice of qkv buffer (cols 2048..3071); z=1 -> obuf; lrun -> Lbuf.
__global__ __launch_bounds__(256) void attn_kernel(const unsigned short* qkv,
                                                   const unsigned short* __restrict__ vT,
                                                   unsigned short* p0,
                                                   unsigned short* __restrict__ p1,
                                                   float* __restrict__ Lbuf) {
    __shared__ __align__(16) unsigned short Kl[2][4096];
    __shared__ __align__(16) unsigned short Vl[2][4096];
    const int t = threadIdx.x, l = t & 63, w = t >> 6;
    const int h = blockIdx.y, z = blockIdx.z;
    const int qrow = blockIdx.x * 128 + w * 32 + (l & 31);
    const int kt0 = z * 32;

    bf16x8 qf[4];
    {
        const unsigned short* qp = qkv + (size_t)qrow * 3072 + h * 64 + ((l >> 5) * 8);
#pragma unroll
        for (int c = 0; c < 4; c++) qf[c] = *(const bf16x8*)(qp + 16 * c);
    }
    const unsigned short* kb = qkv + 1024 + h * 64;
    const unsigned short* vb = vT + (size_t)h * 64 * 4096;

    int off8[4];
#pragma unroll
    for (int c = 0; c < 4; c++)
        off8[c] = (l & 31) * 64 + ((((l >> 5) + 2 * c) ^ (l & 7)) * 8);
    int kst[2], vst[2];
#pragma unroll
    for (int p = 0; p < 2; p++) {
        int c = t + 256 * p;
        int r = c >> 3, b = c & 7;
        kst[p] = r * 3072 + ((b ^ (r & 7)) * 8);
        vst[p] = r * 4096 + ((b ^ (r & 7)) * 8);
    }

    float lrun = 0.f;
    const f32x16 z16 = {0.f, 0.f, 0.f, 0.f, 0.f, 0.f, 0.f, 0.f,
                        0.f, 0.f, 0.f, 0.f, 0.f, 0.f, 0.f, 0.f};
    f32x16 accO[2];
#pragma unroll
    for (int dt = 0; dt < 2; dt++) accO[dt] = z16;

    auto stage = [&](int buf, int kt) {
#pragma unroll
        for (int p = 0; p < 2; p++)
            load_lds16(kb + (size_t)kt * 64 * 3072 + kst[p], &Kl[buf][(t + 256 * p) * 8]);
#pragma unroll
        for (int p = 0; p < 2; p++)
            load_lds16(vb + kt * 64 + vst[p], &Vl[buf][(t + 256 * p) * 8]);
    };

    stage(0, kt0);
    __syncthreads();

    for (int i = 0; i < 32; i++) {
        const int cur = i & 1;
        if (i + 1 < 32) stage(cur ^ 1, kt0 + i + 1);

        f32x16 s[2];
        __builtin_amdgcn_s_setprio(1);
#pragma unroll
        for (int st = 0; st < 2; st++) {
            bf16x8 kf0 = *(const bf16x8*)&Kl[cur][st * 2048 + off8[0]];
            s[st] = __builtin_amdgcn_mfma_f32_32x32x16_bf16(kf0, qf[0], z16, 0, 0, 0);
#pragma unroll
            for (int c = 1; c < 4; c++) {
                bf16x8 kf = *(const bf16x8*)&Kl[cur][st * 2048 + off8[c]];
                s[st] = __builtin_amdgcn_mfma_f32_32x32x16_bf16(kf, qf[c], s[st], 0, 0, 0);
            }
        }
        __builtin_amdgcn_s_setprio(0);

        float rs = 0.f;
#pragma unroll
        for (int st = 0; st < 2; st++)
#pragma unroll
            for (int i2 = 0; i2 < 16; i2++) {
                float p = __builtin_amdgcn_exp2f(s[st][i2]);
                s[st][i2] = p;
                rs += p;
            }
        lrun += rs;

#pragma unroll
        for (int kc = 0; kc < 4; kc++) {
            const int base = 8 * (kc & 1);
            const f32x16& S = s[kc >> 1];
            unsigned w0 = cvtpk(S[base + 0], S[base + 1]);
            unsigned w1 = cvtpk(S[base + 2], S[base + 3]);
            unsigned w2 = cvtpk(S[base + 4], S[base + 5]);
            unsigned w3 = cvtpk(S[base + 6], S[base + 7]);
            asm("v_permlane32_swap_b32 %0, %1" : "+v"(w0), "+v"(w2));
            asm("v_permlane32_swap_b32 %0, %1" : "+v"(w1), "+v"(w3));
            union { unsigned u[4]; bf16x8 v; } pf;
            pf.u[0] = w0; pf.u[1] = w1; pf.u[2] = w2; pf.u[3] = w3;
            __builtin_amdgcn_s_setprio(1);
#pragma unroll
            for (int dt = 0; dt < 2; dt++) {
                bf16x8 vf = *(const bf16x8*)&Vl[cur][dt * 2048 + off8[kc]];
                accO[dt] = __builtin_amdgcn_mfma_f32_32x32x16_bf16(vf, pf.v, accO[dt], 0, 0, 0);
            }
            __builtin_amdgcn_s_setprio(0);
        }
        __syncthreads();
    }

    // write un-normalized partials (bf16) + lrun
    unsigned short* ob = (z == 0 ? p0 + (size_t)qrow * 3072 + 2048 : p1 + (size_t)qrow * 1024)
                         + h * 64 + 4 * (l >> 5);
#pragma unroll
    for (int dt = 0; dt < 2; dt++)
#pragma unroll
        for (int qd = 0; qd < 4; qd++) {
            ushort4 pk;
            pk.x = f2bf(accO[dt][qd * 4 + 0]);
            pk.y = f2bf(accO[dt][qd * 4 + 1]);
            pk.z = f2bf(accO[dt][qd * 4 + 2]);
            pk.w = f2bf(accO[dt][qd * 4 + 3]);
            *(ushort4*)(ob + dt * 32 + qd * 8) = pk;
        }
    lrun += __shfl_xor(lrun, 32, 64);
    if (l < 32)
        Lbuf[(size_t)z * NH * TOK + h * TOK + qrow] = lrun;
}

// ---- combine: obuf = (P0 + P1) / (l0 + l1) ----
__global__ __launch_bounds__(256) void attn_combine(const unsigned short* __restrict__ qkvv,
                                                    unsigned short* __restrict__ obuf,
                                                    const float* __restrict__ Lbuf) {
    const int row = blockIdx.x, t = threadIdx.x;
    const int col = t * 4;
    const int h = col >> 6;
    float inv = 1.0f / (Lbuf[h * TOK + row] + Lbuf[NH * TOK + h * TOK + row]);
    ushort4 a = *(const ushort4*)(qkvv + (size_t)row * 3072 + 2048 + col);
    ushort4 b = *(const ushort4*)(obuf + (size_t)row * 1024 + col);
    ushort4 o;
    o.x = f2bf((bf2f(a.x) + bf2f(b.x)) * inv);
    o.y = f2bf((bf2f(a.y) + bf2f(b.y)) * inv);
    o.z = f2bf((bf2f(a.z) + bf2f(b.z)) * inv);
    o.w = f2bf((bf2f(a.w) + bf2f(b.w)) * inv);
    *(ushort4*)(obuf + (size_t)row * 1024 + col) = o;
}

extern "C" void kernel_launch(void* const* d_in, const int* in_sizes, int n_in,
                              void* d_out, int out_size, void* d_ws, size_t ws_size,
                              hipStream_t stream) {
    const float* x     = (const float*)d_in[0];
    const float* g1    = (const float*)d_in[1];
    const float* g2    = (const float*)d_in[2];
    const float* w_qkv = (const float*)d_in[3];
    const float* w_o   = (const float*)d_in[4];
    const float* w1    = (const float*)d_in[5];
    const float* w2    = (const float*)d_in[6];

    char* ws = (char*)d_ws;
    unsigned short* wqkvT = (unsigned short*)(ws);              // [3072][1024] bf16
    unsigned short* woT   = (unsigned short*)(ws + 6291456);    // [1024][1024]
    unsigned short* w1T   = (unsigned short*)(ws + 8388608);    // [4096][1024]
    unsigned short* w2T   = (unsigned short*)(ws + 16777216);   // [1024][4096]
    unsigned short* hbuf  = (unsigned short*)(ws + 25165824);   // [4096][1024]
    unsigned short* qkv   = (unsigned short*)(ws + 33554432);   // [4096][3072] (v-slice = attn partial-0)
    unsigned short* obuf  = (unsigned short*)(ws + 58720256);   // [4096][1024] (attn partial-1 -> combined)
    float*          x2    = (float*)(ws + 67108864);            // [4096][1024] f32 (attn Lbuf, then wo out)
    unsigned short* abuf  = (unsigned short*)(ws + 83886080);   // [4096][4096]
    unsigned short* vTb   = (unsigned short*)(ws + 83886080);   // [1024][4096] (aliases abuf; dead before w1 GEMM)

    dim3 b256(256), b512(512);
    wT_kernel<<<dim3(CH / 32, 3 * CH / 32), b256, 0, stream>>>(w_qkv, wqkvT, CH, 3 * CH);
    wT_kernel<<<dim3(CH / 32, CH / 32),     b256, 0, stream>>>(w_o,   woT,   CH, CH);
    wT_kernel<<<dim3(CH / 32, FF / 32),     b256, 0, stream>>>(w1,    w1T,   CH, FF);
    wT_kernel<<<dim3(FF / 32, CH / 32),     b256, 0, stream>>>(w2,    w2T,   FF, CH);

    rms_kernel<<<TOK, b256, 0, stream>>>(x, g1, hbuf);
    // qkv: 256^2 phase-interleaved GEMM; q-scale + fused V-transpose into vTb
    gemm256<3><<<(TOK / 256) * (3 * CH / 256), b512, 0, stream>>>(hbuf, wqkvT, qkv, vTb, TOK, 3 * CH, CH);
    // attn: split-KV x2 for occupancy; un-normalized bf16 partials; Lbuf in x2 (dead until wo)
    attn_kernel<<<dim3(TOK / 128, NH, 2), b256, 0, stream>>>(qkv, vTb, qkv, obuf, x2);
    attn_combine<<<TOK, b256, 0, stream>>>(qkv, obuf, x2);
    gemm_bt<64, 64, 2><<<(TOK / 64) * (CH / 64), b256, 0, stream>>>(obuf, woT, x2, x, TOK, CH, CH);
    rms_kernel<<<TOK, b256, 0, stream>>>(x2, g2, hbuf);
    // w1: 256^2 phase-interleaved GEMM with gelu epilogue
    gemm256<1><<<(TOK / 256) * (FF / 256), b512, 0, stream>>>(hbuf, w1T, abuf, nullptr, TOK, FF, CH);
    gemm_bt<64, 64, 2><<<(TOK / 64) * (CH / 64), b256, 0, stream>>>(abuf, w2T, (float*)d_out, x2, TOK, CH, FF);
}

// Round 14
// 280.647 us; speedup vs baseline: 1.0476x; 1.0476x over previous
//
#include <hip/hip_runtime.h>
#include <stdint.h>

#define TOK 4096
#define CH  1024
#define NH  16
#define HD  64
#define FF  4096

typedef __attribute__((ext_vector_type(8))) short bf16x8;
typedef __attribute__((ext_vector_type(4))) float f32x4;
typedef __attribute__((ext_vector_type(16))) float f32x16;

__device__ __forceinline__ unsigned short f2bf(float f) {
    union { float f; unsigned u; } v; v.f = f;
    unsigned u = v.u;
    u += 0x7fffu + ((u >> 16) & 1u);
    return (unsigned short)(u >> 16);
}

__device__ __forceinline__ unsigned cvtpk(float a, float b) {
    unsigned r;
    asm("v_cvt_pk_bf16_f32 %0, %1, %2" : "=v"(r) : "v"(a), "v"(b));
    return r;
}

__device__ __forceinline__ void load_lds16(const void* g, void* l) {
    __builtin_amdgcn_global_load_lds(
        (const __attribute__((address_space(1))) unsigned int*)g,
        (__attribute__((address_space(3))) unsigned int*)l, 16, 0, 0);
}

// counted-vmcnt barrier: N loads may stay in flight
template<int N> __device__ __forceinline__ void wait_vm_lgkm0() {
    if constexpr (N == 0)      asm volatile("s_waitcnt vmcnt(0) lgkmcnt(0)" ::: "memory");
    else if constexpr (N == 4) asm volatile("s_waitcnt vmcnt(4) lgkmcnt(0)" ::: "memory");
    else if constexpr (N == 8) asm volatile("s_waitcnt vmcnt(8) lgkmcnt(0)" ::: "memory");
    __builtin_amdgcn_sched_barrier(0);
    __builtin_amdgcn_s_barrier();
}

__device__ __forceinline__ float gelu_tanh(float u) {
    float z = 0.7978845608028654f * (u + 0.044715f * u * u * u);
    float e = __expf(2.0f * z);
    return 0.5f * u * (1.0f + (1.0f - 2.0f / (e + 1.0f)));
}

// ---- weight transpose+cast: in [K][Nn] f32 -> out [Nn][K] bf16 (vectorized) ----
__global__ __launch_bounds__(256) void wT_kernel(const float* __restrict__ in,
                                                 unsigned short* __restrict__ out,
                                                 int K, int Nn) {
    __shared__ float tile[32][36];
    int k0 = blockIdx.x * 32, n0 = blockIdx.y * 32;
    int t = threadIdx.x;
    int r = t >> 3, c4 = (t & 7) * 4;
    float4 v = *(const float4*)(in + (size_t)(k0 + r) * Nn + n0 + c4);
    *(float4*)&tile[r][c4] = v;
    __syncthreads();
    ushort4 o;
    o.x = f2bf(tile[c4 + 0][r]);
    o.y = f2bf(tile[c4 + 1][r]);
    o.z = f2bf(tile[c4 + 2][r]);
    o.w = f2bf(tile[c4 + 3][r]);
    *(ushort4*)(out + (size_t)(n0 + r) * K + k0 + c4) = o;
}

// ---- rmsnorm: f32 row -> bf16 row ----
__global__ __launch_bounds__(256) void rms_kernel(const float* __restrict__ x,
                                                  const float* __restrict__ g,
                                                  unsigned short* __restrict__ out) {
    int row = blockIdx.x, t = threadIdx.x;
    const float4* xr = (const float4*)(x + (size_t)row * CH);
    float4 v = xr[t];
    float ss = v.x * v.x + v.y * v.y + v.z * v.z + v.w * v.w;
#pragma unroll
    for (int m = 32; m; m >>= 1) ss += __shfl_xor(ss, m, 64);
    __shared__ float wsum[4];
    if ((t & 63) == 0) wsum[t >> 6] = ss;
    __syncthreads();
    float inv = rsqrtf((wsum[0] + wsum[1] + wsum[2] + wsum[3]) * (1.0f / CH) + 1e-6f);
    float4 gv = ((const float4*)g)[t];
    ushort4 o;
    o.x = f2bf(v.x * inv * gv.x);
    o.y = f2bf(v.y * inv * gv.y);
    o.z = f2bf(v.z * inv * gv.z);
    o.w = f2bf(v.w * inv * gv.w);
    ((ushort4*)(out + (size_t)row * CH))[t] = o;
}

// ---- small GEMM (wo/w2): C = A * Bt^T, 64x64 tile, 4 waves ----
// 4-buffer LDS, 2 K-tiles per drain+barrier.
template<int BM, int BN, int EPI>
__global__ __launch_bounds__(256) void gemm_bt(const unsigned short* __restrict__ A,
                                               const unsigned short* __restrict__ Bt,
                                               void* __restrict__ outp,
                                               const float* __restrict__ resid,
                                               int M, int Nn, int K) {
    __shared__ __align__(16) unsigned short ldsA[4][BM * 32];
    __shared__ __align__(16) unsigned short ldsB[4][BN * 32];
    const int t = threadIdx.x, l = t & 63, w = t >> 6;
    const int nbn = Nn / BN;
    const int bid = blockIdx.x, nwg = gridDim.x, cpx = nwg >> 3;
    const int swz = (bid & 7) * cpx + (bid >> 3);
    const int bm = swz / nbn, bn = swz % nbn;
    const int wr = w >> 1, wc = w & 1;
    constexpr int MF = BM / 32, NF = BN / 32;
    const unsigned short* Ag = A + (size_t)bm * BM * K;
    const unsigned short* Bg = Bt + (size_t)bn * BN * K;

    f32x4 acc[MF][NF];
#pragma unroll
    for (int m = 0; m < MF; m++)
#pragma unroll
        for (int n = 0; n < NF; n++) acc[m][n] = {0.f, 0.f, 0.f, 0.f};

    auto stage = [&](int kt) {
        const int buf = kt & 3;
#pragma unroll
        for (int p = 0; p < BM / 64; p++) {
            int c = t + 256 * p;
            load_lds16(Ag + (size_t)(c >> 2) * K + kt * 32 + (c & 3) * 8, &ldsA[buf][c * 8]);
        }
#pragma unroll
        for (int p = 0; p < BN / 64; p++) {
            int c = t + 256 * p;
            load_lds16(Bg + (size_t)(c >> 2) * K + kt * 32 + (c & 3) * 8, &ldsB[buf][c * 8]);
        }
    };

    auto compute = [&](int kt) {
        const int buf = kt & 3;
        bf16x8 af[MF], bfr[NF];
#pragma unroll
        for (int m = 0; m < MF; m++)
            af[m] = *(const bf16x8*)&ldsA[buf][(wr * (BM / 2) + m * 16 + (l & 15)) * 32 + (l >> 4) * 8];
#pragma unroll
        for (int n = 0; n < NF; n++)
            bfr[n] = *(const bf16x8*)&ldsB[buf][(wc * (BN / 2) + n * 16 + (l & 15)) * 32 + (l >> 4) * 8];
#pragma unroll
        for (int m = 0; m < MF; m++)
#pragma unroll
            for (int n = 0; n < NF; n++)
                acc[m][n] = __builtin_amdgcn_mfma_f32_16x16x32_bf16(af[m], bfr[n], acc[m][n], 0, 0, 0);
    };

    const int nkt = K >> 5;
    stage(0); stage(1);
    for (int kt = 0; kt < nkt; kt += 2) {
        wait_vm_lgkm0<0>();                  // tiles kt,kt+1 landed; prior reads drained
        if (kt + 2 < nkt) { stage(kt + 2); stage(kt + 3); }
        compute(kt);
        compute(kt + 1);
    }

    const int r0 = bm * BM + wr * (BM / 2), c0 = bn * BN + wc * (BN / 2);
#pragma unroll
    for (int m = 0; m < MF; m++)
#pragma unroll
        for (int n = 0; n < NF; n++)
#pragma unroll
            for (int r = 0; r < 4; r++) {
                int rr = r0 + m * 16 + (l >> 4) * 4 + r;
                int cc = c0 + n * 16 + (l & 15);
                float v = acc[m][n][r];
                if (EPI == 0) {
                    ((unsigned short*)outp)[(size_t)rr * Nn + cc] = f2bf(v);
                } else if (EPI == 1) {
                    ((unsigned short*)outp)[(size_t)rr * Nn + cc] = f2bf(gelu_tanh(v));
                } else {
                    ((float*)outp)[(size_t)rr * Nn + cc] = resid[(size_t)rr * Nn + cc] + v;
                }
            }
}

// ---- big GEMM (qkv/w1): 256x256 tile, BK=64, 8 waves (2M x 4N), 512 threads ----
// Phase-interleaved, st_16x32 swizzle, setprio; next tile's halves issued in phases 0-1
// (max landing window before the drain-0 tile boundary).
template<int EPI>
__global__ __launch_bounds__(512) void gemm256(const unsigned short* __restrict__ A,
                                               const unsigned short* __restrict__ Bt,
                                               void* __restrict__ outp,
                                               unsigned short* __restrict__ vout,
                                               int M, int Nn, int K) {
    __shared__ __align__(16) unsigned short lds[2][4][8192];
    const int t = threadIdx.x, l = t & 63, w = t >> 6;
    const int wr = w >> 2, wc = w & 3;
    const int nbn = Nn >> 8;
    const int bid = blockIdx.x, nwg = gridDim.x, cpx = nwg >> 3;
    const int swz = (bid & 7) * cpx + (bid >> 3);
    const int bm = swz / nbn, bn = swz % nbn;

    const int lbase = (((l & 15) * 64 + (l >> 4) * 16)) ^ (((l >> 3) & 1) << 5);

    int srow[2], scol[2];
#pragma unroll
    for (int L = 0; L < 2; L++) {
        int g = t + L * 512;
        int s = g >> 6;
        int wb = ((g & 63) * 16) ^ (((g >> 5) & 1) << 5);
        srow[L] = (s >> 1) * 16 + (wb >> 6);
        scol[L] = (s & 1) * 32 + ((wb & 63) >> 1);
    }

    const unsigned short* Asrc = A + (size_t)(bm * 256) * K;
    const unsigned short* Bsrc = Bt + (size_t)(bn * 256) * K;

    auto stage_half = [&](int j) {
        const int kt = j >> 2, slot = j & 3;
        const unsigned short* base = (slot < 2 ? Asrc : Bsrc) + (size_t)((slot & 1) * 128) * K;
#pragma unroll
        for (int L = 0; L < 2; L++)
            load_lds16(base + (size_t)srow[L] * K + kt * 64 + scol[L],
                       &lds[kt & 1][slot][(t + L * 512) * 8]);
    };

    f32x4 acc[8][4];
#pragma unroll
    for (int m = 0; m < 8; m++)
#pragma unroll
        for (int n = 0; n < 4; n++) acc[m][n] = {0.f, 0.f, 0.f, 0.f};

    const int nkt = K >> 6;
    stage_half(0); stage_half(1); stage_half(2); stage_half(3);

    for (int kt = 0; kt < nkt; kt++) {
        wait_vm_lgkm0<0>();
        const char* Abase = (const char*)&lds[kt & 1][wr][0];
        const char* Bbase = (const char*)&lds[kt & 1][2 + (wc >> 1)][0];
        bf16x8 bfr[4][2];
#pragma unroll
        for (int q = 0; q < 4; q++) {
            if (q == 0) {
#pragma unroll
                for (int n = 0; n < 4; n++)
#pragma unroll
                    for (int ks = 0; ks < 2; ks++)
                        bfr[n][ks] = *(const bf16x8*)(Bbase + ((((wc & 1) * 4 + n) * 2 + ks) * 1024 + lbase));
            }
            bf16x8 af[2][2];
#pragma unroll
            for (int mi = 0; mi < 2; mi++)
#pragma unroll
                for (int ks = 0; ks < 2; ks++)
                    af[mi][ks] = *(const bf16x8*)(Abase + (((q * 2 + mi) * 2 + ks) * 1024 + lbase));
            // issue next tile's halves early: 0,1 at q=0; 2,3 at q=1 (writes opposite dbuf)
            if (kt + 1 < nkt && q < 2) {
                stage_half((kt + 1) * 4 + 2 * q);
                stage_half((kt + 1) * 4 + 2 * q + 1);
            }
            __builtin_amdgcn_s_barrier();
            __builtin_amdgcn_s_setprio(1);
#pragma unroll
            for (int mi = 0; mi < 2; mi++)
#pragma unroll
                for (int n = 0; n < 4; n++) {
                    acc[q * 2 + mi][n] = __builtin_amdgcn_mfma_f32_16x16x32_bf16(af[mi][0], bfr[n][0], acc[q * 2 + mi][n], 0, 0, 0);
                    acc[q * 2 + mi][n] = __builtin_amdgcn_mfma_f32_16x16x32_bf16(af[mi][1], bfr[n][1], acc[q * 2 + mi][n], 0, 0, 0);
                }
            __builtin_amdgcn_s_setprio(0);
            __builtin_amdgcn_s_barrier();
        }
    }

    const int r0 = bm * 256 + wr * 128, c0 = bn * 256 + wc * 64;
    const bool vpart = (EPI == 3) && (c0 >= 2048);
#pragma unroll
    for (int m = 0; m < 8; m++)
#pragma unroll
        for (int n = 0; n < 4; n++) {
            if (vpart) {
                int cc = c0 + n * 16 + (l & 15);
                int rrb = r0 + m * 16 + (l >> 4) * 4;
                ushort4 pk;
                pk.x = f2bf(acc[m][n][0]);
                pk.y = f2bf(acc[m][n][1]);
                pk.z = f2bf(acc[m][n][2]);
                pk.w = f2bf(acc[m][n][3]);
                *(ushort4*)(vout + (size_t)(cc - 2048) * 4096 + rrb) = pk;
            } else {
#pragma unroll
                for (int r = 0; r < 4; r++) {
                    int rr = r0 + m * 16 + (l >> 4) * 4 + r;
                    int cc = c0 + n * 16 + (l & 15);
                    float v = acc[m][n][r];
                    if (EPI == 1) {
                        ((unsigned short*)outp)[(size_t)rr * Nn + cc] = f2bf(gelu_tanh(v));
                    } else {
                        float sc = (cc < 1024) ? 0.180336880f : 1.0f;   // 0.125*log2(e)
                        ((unsigned short*)outp)[(size_t)rr * Nn + cc] = f2bf(v * sc);
                    }
                }
            }
        }
}

// ---- flash attention, swapped-operand 32x32, no-max exp2 softmax (round-12 best) ----
// KVBLK=128: 4-buffer LDS, one drain+barrier per TWO 64-key tiles.
__global__ __launch_bounds__(256) void attn_kernel(const unsigned short* __restrict__ qkv,
                                                   const unsigned short* __restrict__ vT,
                                                   unsigned short* __restrict__ o) {
    __shared__ __align__(16) unsigned short Kl[4][4096];
    __shared__ __align__(16) unsigned short Vl[4][4096];
    const int t = threadIdx.x, l = t & 63, w = t >> 6;
    const int h = blockIdx.y;
    const int qrow = blockIdx.x * 128 + w * 32 + (l & 31);

    bf16x8 qf[4];
    {
        const unsigned short* qp = qkv + (size_t)qrow * 3072 + h * 64 + ((l >> 5) * 8);
#pragma unroll
        for (int c = 0; c < 4; c++) qf[c] = *(const bf16x8*)(qp + 16 * c);
    }
    const unsigned short* kb = qkv + 1024 + h * 64;
    const unsigned short* vb = vT + (size_t)h * 64 * 4096;

    int off8[4];
#pragma unroll
    for (int c = 0; c < 4; c++)
        off8[c] = (l & 31) * 64 + ((((l >> 5) + 2 * c) ^ (l & 7)) * 8);
    int kst[2], vst[2];
#pragma unroll
    for (int p = 0; p < 2; p++) {
        int c = t + 256 * p;
        int r = c >> 3, b = c & 7;
        kst[p] = r * 3072 + ((b ^ (r & 7)) * 8);
        vst[p] = r * 4096 + ((b ^ (r & 7)) * 8);
    }

    float lrun = 0.f;
    const f32x16 z16 = {0.f, 0.f, 0.f, 0.f, 0.f, 0.f, 0.f, 0.f,
                        0.f, 0.f, 0.f, 0.f, 0.f, 0.f, 0.f, 0.f};
    f32x16 accO[2];
#pragma unroll
    for (int dt = 0; dt < 2; dt++) accO[dt] = z16;

    auto stage = [&](int tile) {
        const int buf = tile & 3;
#pragma unroll
        for (int p = 0; p < 2; p++)
            load_lds16(kb + (size_t)tile * 64 * 3072 + kst[p], &Kl[buf][(t + 256 * p) * 8]);
#pragma unroll
        for (int p = 0; p < 2; p++)
            load_lds16(vb + tile * 64 + vst[p], &Vl[buf][(t + 256 * p) * 8]);
    };

    auto compute = [&](int kt) {
        const int cur = kt & 3;
        f32x16 s[2];
        __builtin_amdgcn_s_setprio(1);
#pragma unroll
        for (int st = 0; st < 2; st++) {
            bf16x8 kf0 = *(const bf16x8*)&Kl[cur][st * 2048 + off8[0]];
            s[st] = __builtin_amdgcn_mfma_f32_32x32x16_bf16(kf0, qf[0], z16, 0, 0, 0);
#pragma unroll
            for (int c = 1; c < 4; c++) {
                bf16x8 kf = *(const bf16x8*)&Kl[cur][st * 2048 + off8[c]];
                s[st] = __builtin_amdgcn_mfma_f32_32x32x16_bf16(kf, qf[c], s[st], 0, 0, 0);
            }
        }
        __builtin_amdgcn_s_setprio(0);

        float rs = 0.f;
#pragma unroll
        for (int st = 0; st < 2; st++)
#pragma unroll
            for (int i = 0; i < 16; i++) {
                float p = __builtin_amdgcn_exp2f(s[st][i]);
                s[st][i] = p;
                rs += p;
            }
        lrun += rs;

#pragma unroll
        for (int kc = 0; kc < 4; kc++) {
            const int base = 8 * (kc & 1);
            const f32x16& S = s[kc >> 1];
            unsigned w0 = cvtpk(S[base + 0], S[base + 1]);
            unsigned w1 = cvtpk(S[base + 2], S[base + 3]);
            unsigned w2 = cvtpk(S[base + 4], S[base + 5]);
            unsigned w3 = cvtpk(S[base + 6], S[base + 7]);
            asm("v_permlane32_swap_b32 %0, %1" : "+v"(w0), "+v"(w2));
            asm("v_permlane32_swap_b32 %0, %1" : "+v"(w1), "+v"(w3));
            union { unsigned u[4]; bf16x8 v; } pf;
            pf.u[0] = w0; pf.u[1] = w1; pf.u[2] = w2; pf.u[3] = w3;
            __builtin_amdgcn_s_setprio(1);
#pragma unroll
            for (int dt = 0; dt < 2; dt++) {
                bf16x8 vf = *(const bf16x8*)&Vl[cur][dt * 2048 + off8[kc]];
                accO[dt] = __builtin_amdgcn_mfma_f32_32x32x16_bf16(vf, pf.v, accO[dt], 0, 0, 0);
            }
            __builtin_amdgcn_s_setprio(0);
        }
    };

    stage(0); stage(1);
    for (int kt = 0; kt < 64; kt += 2) {
        wait_vm_lgkm0<0>();
        if (kt + 2 < 64) { stage(kt + 2); stage(kt + 3); }
        compute(kt);
        compute(kt + 1);
    }

    lrun += __shfl_xor(lrun, 32, 64);
    float inv = 1.0f / lrun;
    unsigned short* ob = o + (size_t)qrow * CH + h * 64 + 4 * (l >> 5);
#pragma unroll
    for (int dt = 0; dt < 2; dt++)
#pragma unroll
        for (int qd = 0; qd < 4; qd++) {
            ushort4 pk;
            pk.x = f2bf(accO[dt][qd * 4 + 0] * inv);
            pk.y = f2bf(accO[dt][qd * 4 + 1] * inv);
            pk.z = f2bf(accO[dt][qd * 4 + 2] * inv);
            pk.w = f2bf(accO[dt][qd * 4 + 3] * inv);
            *(ushort4*)(ob + dt * 32 + qd * 8) = pk;
        }
}

extern "C" void kernel_launch(void* const* d_in, const int* in_sizes, int n_in,
                              void* d_out, int out_size, void* d_ws, size_t ws_size,
                              hipStream_t stream) {
    const float* x     = (const float*)d_in[0];
    const float* g1    = (const float*)d_in[1];
    const float* g2    = (const float*)d_in[2];
    const float* w_qkv = (const float*)d_in[3];
    const float* w_o   = (const float*)d_in[4];
    const float* w1    = (const float*)d_in[5];
    const float* w2    = (const float*)d_in[6];

    char* ws = (char*)d_ws;
    unsigned short* wqkvT = (unsigned short*)(ws);              // [3072][1024] bf16
    unsigned short* woT   = (unsigned short*)(ws + 6291456);    // [1024][1024]
    unsigned short* w1T   = (unsigned short*)(ws + 8388608);    // [4096][1024]
    unsigned short* w2T   = (unsigned short*)(ws + 16777216);   // [1024][4096]
    unsigned short* hbuf  = (unsigned short*)(ws + 25165824);   // [4096][1024]
    unsigned short* qkv   = (unsigned short*)(ws + 33554432);   // [4096][3072] (v-part unused)
    unsigned short* obuf  = (unsigned short*)(ws + 58720256);   // [4096][1024]
    float*          x2    = (float*)(ws + 67108864);            // [4096][1024] f32
    unsigned short* abuf  = (unsigned short*)(ws + 83886080);   // [4096][4096]
    unsigned short* vTb   = (unsigned short*)(ws + 83886080);   // [1024][4096] (aliases abuf; dead before w1 GEMM)

    dim3 b256(256), b512(512);
    wT_kernel<<<dim3(CH / 32, 3 * CH / 32), b256, 0, stream>>>(w_qkv, wqkvT, CH, 3 * CH);
    wT_kernel<<<dim3(CH / 32, CH / 32),     b256, 0, stream>>>(w_o,   woT,   CH, CH);
    wT_kernel<<<dim3(CH / 32, FF / 32),     b256, 0, stream>>>(w1,    w1T,   CH, FF);
    wT_kernel<<<dim3(FF / 32, CH / 32),     b256, 0, stream>>>(w2,    w2T,   FF, CH);

    rms_kernel<<<TOK, b256, 0, stream>>>(x, g1, hbuf);
    // qkv: 256^2 phase-interleaved GEMM; q-scale + fused V-transpose into vTb
    gemm256<3><<<(TOK / 256) * (3 * CH / 256), b512, 0, stream>>>(hbuf, wqkvT, qkv, vTb, TOK, 3 * CH, CH);
    attn_kernel<<<dim3(TOK / 128, NH), b256, 0, stream>>>(qkv, vTb, obuf);
    gemm_bt<64, 64, 2><<<(TOK / 64) * (CH / 64), b256, 0, stream>>>(obuf, woT, x2, x, TOK, CH, CH);
    rms_kernel<<<TOK, b256, 0, stream>>>(x2, g2, hbuf);
    // w1: 256^2 phase-interleaved GEMM with gelu epilogue
    gemm256<1><<<(TOK / 256) * (FF / 256), b512, 0, stream>>>(hbuf, w1T, abuf, nullptr, TOK, FF, CH);
    gemm_bt<64, 64, 2><<<(TOK / 64) * (CH / 64), b256, 0, stream>>>(abuf, w2T, (float*)d_out, x2, TOK, CH, FF);
}

// Round 15
// 276.425 us; speedup vs baseline: 1.0636x; 1.0153x over previous
//
#include <hip/hip_runtime.h>
#include <stdint.h>

#define TOK 4096
#define CH  1024
#define NH  16
#define HD  64
#define FF  4096

typedef __attribute__((ext_vector_type(8))) short bf16x8;
typedef __attribute__((ext_vector_type(4))) float f32x4;
typedef __attribute__((ext_vector_type(16))) float f32x16;

__device__ __forceinline__ unsigned short f2bf(float f) {
    union { float f; unsigned u; } v; v.f = f;
    unsigned u = v.u;
    u += 0x7fffu + ((u >> 16) & 1u);
    return (unsigned short)(u >> 16);
}

__device__ __forceinline__ unsigned cvtpk(float a, float b) {
    unsigned r;
    asm("v_cvt_pk_bf16_f32 %0, %1, %2" : "=v"(r) : "v"(a), "v"(b));
    return r;
}

__device__ __forceinline__ void load_lds16(const void* g, void* l) {
    __builtin_amdgcn_global_load_lds(
        (const __attribute__((address_space(1))) unsigned int*)g,
        (__attribute__((address_space(3))) unsigned int*)l, 16, 0, 0);
}

// counted-vmcnt barrier: N loads may stay in flight
template<int N> __device__ __forceinline__ void wait_vm_lgkm0() {
    if constexpr (N == 0)      asm volatile("s_waitcnt vmcnt(0) lgkmcnt(0)" ::: "memory");
    else if constexpr (N == 4) asm volatile("s_waitcnt vmcnt(4) lgkmcnt(0)" ::: "memory");
    else if constexpr (N == 8) asm volatile("s_waitcnt vmcnt(8) lgkmcnt(0)" ::: "memory");
    __builtin_amdgcn_sched_barrier(0);
    __builtin_amdgcn_s_barrier();
}

__device__ __forceinline__ float gelu_tanh(float u) {
    float z = 0.7978845608028654f * (u + 0.044715f * u * u * u);
    float e = __expf(2.0f * z);
    return 0.5f * u * (1.0f + (1.0f - 2.0f / (e + 1.0f)));
}

// ---- weight transpose+cast: in [K][Nn] f32 -> out [Nn][K] bf16 (vectorized) ----
__global__ __launch_bounds__(256) void wT_kernel(const float* __restrict__ in,
                                                 unsigned short* __restrict__ out,
                                                 int K, int Nn) {
    __shared__ float tile[32][36];
    int k0 = blockIdx.x * 32, n0 = blockIdx.y * 32;
    int t = threadIdx.x;
    int r = t >> 3, c4 = (t & 7) * 4;
    float4 v = *(const float4*)(in + (size_t)(k0 + r) * Nn + n0 + c4);
    *(float4*)&tile[r][c4] = v;
    __syncthreads();
    ushort4 o;
    o.x = f2bf(tile[c4 + 0][r]);
    o.y = f2bf(tile[c4 + 1][r]);
    o.z = f2bf(tile[c4 + 2][r]);
    o.w = f2bf(tile[c4 + 3][r]);
    *(ushort4*)(out + (size_t)(n0 + r) * K + k0 + c4) = o;
}

// ---- rmsnorm: f32 row -> bf16 row ----
__global__ __launch_bounds__(256) void rms_kernel(const float* __restrict__ x,
                                                  const float* __restrict__ g,
                                                  unsigned short* __restrict__ out) {
    int row = blockIdx.x, t = threadIdx.x;
    const float4* xr = (const float4*)(x + (size_t)row * CH);
    float4 v = xr[t];
    float ss = v.x * v.x + v.y * v.y + v.z * v.z + v.w * v.w;
#pragma unroll
    for (int m = 32; m; m >>= 1) ss += __shfl_xor(ss, m, 64);
    __shared__ float wsum[4];
    if ((t & 63) == 0) wsum[t >> 6] = ss;
    __syncthreads();
    float inv = rsqrtf((wsum[0] + wsum[1] + wsum[2] + wsum[3]) * (1.0f / CH) + 1e-6f);
    float4 gv = ((const float4*)g)[t];
    ushort4 o;
    o.x = f2bf(v.x * inv * gv.x);
    o.y = f2bf(v.y * inv * gv.y);
    o.z = f2bf(v.z * inv * gv.z);
    o.w = f2bf(v.w * inv * gv.w);
    ((ushort4*)(out + (size_t)row * CH))[t] = o;
}

// ---- small GEMM (wo/w2): C = A * Bt^T, 64x64 tile, 4 waves ----
// 4-buffer LDS, 2 K-tiles per drain+barrier.
template<int BM, int BN, int EPI>
__global__ __launch_bounds__(256) void gemm_bt(const unsigned short* __restrict__ A,
                                               const unsigned short* __restrict__ Bt,
                                               void* __restrict__ outp,
                                               const float* __restrict__ resid,
                                               int M, int Nn, int K) {
    __shared__ __align__(16) unsigned short ldsA[4][BM * 32];
    __shared__ __align__(16) unsigned short ldsB[4][BN * 32];
    const int t = threadIdx.x, l = t & 63, w = t >> 6;
    const int nbn = Nn / BN;
    const int bid = blockIdx.x, nwg = gridDim.x, cpx = nwg >> 3;
    const int swz = (bid & 7) * cpx + (bid >> 3);
    const int bm = swz / nbn, bn = swz % nbn;
    const int wr = w >> 1, wc = w & 1;
    constexpr int MF = BM / 32, NF = BN / 32;
    const unsigned short* Ag = A + (size_t)bm * BM * K;
    const unsigned short* Bg = Bt + (size_t)bn * BN * K;

    f32x4 acc[MF][NF];
#pragma unroll
    for (int m = 0; m < MF; m++)
#pragma unroll
        for (int n = 0; n < NF; n++) acc[m][n] = {0.f, 0.f, 0.f, 0.f};

    auto stage = [&](int kt) {
        const int buf = kt & 3;
#pragma unroll
        for (int p = 0; p < BM / 64; p++) {
            int c = t + 256 * p;
            load_lds16(Ag + (size_t)(c >> 2) * K + kt * 32 + (c & 3) * 8, &ldsA[buf][c * 8]);
        }
#pragma unroll
        for (int p = 0; p < BN / 64; p++) {
            int c = t + 256 * p;
            load_lds16(Bg + (size_t)(c >> 2) * K + kt * 32 + (c & 3) * 8, &ldsB[buf][c * 8]);
        }
    };

    auto compute = [&](int kt) {
        const int buf = kt & 3;
        bf16x8 af[MF], bfr[NF];
#pragma unroll
        for (int m = 0; m < MF; m++)
            af[m] = *(const bf16x8*)&ldsA[buf][(wr * (BM / 2) + m * 16 + (l & 15)) * 32 + (l >> 4) * 8];
#pragma unroll
        for (int n = 0; n < NF; n++)
            bfr[n] = *(const bf16x8*)&ldsB[buf][(wc * (BN / 2) + n * 16 + (l & 15)) * 32 + (l >> 4) * 8];
#pragma unroll
        for (int m = 0; m < MF; m++)
#pragma unroll
            for (int n = 0; n < NF; n++)
                acc[m][n] = __builtin_amdgcn_mfma_f32_16x16x32_bf16(af[m], bfr[n], acc[m][n], 0, 0, 0);
    };

    const int nkt = K >> 5;
    stage(0); stage(1);
    for (int kt = 0; kt < nkt; kt += 2) {
        wait_vm_lgkm0<0>();
        if (kt + 2 < nkt) { stage(kt + 2); stage(kt + 3); }
        compute(kt);
        compute(kt + 1);
    }

    const int r0 = bm * BM + wr * (BM / 2), c0 = bn * BN + wc * (BN / 2);
#pragma unroll
    for (int m = 0; m < MF; m++)
#pragma unroll
        for (int n = 0; n < NF; n++)
#pragma unroll
            for (int r = 0; r < 4; r++) {
                int rr = r0 + m * 16 + (l >> 4) * 4 + r;
                int cc = c0 + n * 16 + (l & 15);
                float v = acc[m][n][r];
                if (EPI == 0) {
                    ((unsigned short*)outp)[(size_t)rr * Nn + cc] = f2bf(v);
                } else if (EPI == 1) {
                    ((unsigned short*)outp)[(size_t)rr * Nn + cc] = f2bf(gelu_tanh(v));
                } else {
                    ((float*)outp)[(size_t)rr * Nn + cc] = resid[(size_t)rr * Nn + cc] + v;
                }
            }
}

// ---- qkv GEMM: 128x128 tile, BK=64, 8 waves (2M x 4N), wave out 64x32 ----
// 64KB LDS -> 2 blocks/CU (4 waves/SIMD); st_16x32 swizzle; early-issue staging.
// EPI==3: cols<1024 scaled by scale*log2e; cols>=2048 transposed into vout[d][tok].
template<int EPI>
__global__ __launch_bounds__(512) void gemm128(const unsigned short* __restrict__ A,
                                               const unsigned short* __restrict__ Bt,
                                               void* __restrict__ outp,
                                               unsigned short* __restrict__ vout,
                                               int M, int Nn, int K) {
    __shared__ __align__(16) unsigned short lds[2][2][8192];   // [dbuf][A,B][128x64 swz]
    const int t = threadIdx.x, l = t & 63, w = t >> 6;
    const int wr = w >> 2, wc = w & 3;            // 2 x 4 wave grid
    const int nbn = Nn >> 7;
    const int bid = blockIdx.x, nwg = gridDim.x, cpx = nwg >> 3;
    const int swz = (bid & 7) * cpx + (bid >> 3);
    const int bm = swz / nbn, bn = swz % nbn;

    const int lbase = (((l & 15) * 64 + (l >> 4) * 16)) ^ (((l >> 3) & 1) << 5);

    int srow[2], scol[2];
#pragma unroll
    for (int L = 0; L < 2; L++) {
        int g = t + L * 512;
        int s = g >> 6;
        int wb = ((g & 63) * 16) ^ (((g >> 5) & 1) << 5);
        srow[L] = (s >> 1) * 16 + (wb >> 6);
        scol[L] = (s & 1) * 32 + ((wb & 63) >> 1);
    }

    const unsigned short* Asrc = A + (size_t)(bm * 128) * K;
    const unsigned short* Bsrc = Bt + (size_t)(bn * 128) * K;

    auto stage_half = [&](int j) {                 // j = kt*2 + slot (0=A, 1=B)
        const int kt = j >> 1, slot = j & 1;
        const unsigned short* base = slot ? Bsrc : Asrc;
#pragma unroll
        for (int L = 0; L < 2; L++)
            load_lds16(base + (size_t)srow[L] * K + kt * 64 + scol[L],
                       &lds[kt & 1][slot][(t + L * 512) * 8]);
    };

    f32x4 acc[4][2];
#pragma unroll
    for (int m = 0; m < 4; m++)
#pragma unroll
        for (int n = 0; n < 2; n++) acc[m][n] = {0.f, 0.f, 0.f, 0.f};

    const int nkt = K >> 6;
    stage_half(0); stage_half(1);                  // tile 0

    for (int kt = 0; kt < nkt; kt++) {
        wait_vm_lgkm0<0>();                        // tile kt landed
        const char* Abase = (const char*)&lds[kt & 1][0][0];
        const char* Bbase = (const char*)&lds[kt & 1][1][0];
        bf16x8 bfr[2][2];
#pragma unroll
        for (int q = 0; q < 4; q++) {
            if (q == 0) {
#pragma unroll
                for (int n = 0; n < 2; n++)
#pragma unroll
                    for (int ks = 0; ks < 2; ks++)
                        bfr[n][ks] = *(const bf16x8*)(Bbase + (((wc * 2 + n) * 2 + ks) * 1024 + lbase));
            }
            bf16x8 af[2];
#pragma unroll
            for (int ks = 0; ks < 2; ks++)
                af[ks] = *(const bf16x8*)(Abase + (((wr * 4 + q) * 2 + ks) * 1024 + lbase));
            if (kt + 1 < nkt && q < 2) stage_half((kt + 1) * 2 + q);   // A@q0, B@q1 -> other dbuf
            __builtin_amdgcn_s_barrier();
            __builtin_amdgcn_s_setprio(1);
#pragma unroll
            for (int n = 0; n < 2; n++) {
                acc[q][n] = __builtin_amdgcn_mfma_f32_16x16x32_bf16(af[0], bfr[n][0], acc[q][n], 0, 0, 0);
                acc[q][n] = __builtin_amdgcn_mfma_f32_16x16x32_bf16(af[1], bfr[n][1], acc[q][n], 0, 0, 0);
            }
            __builtin_amdgcn_s_setprio(0);
            __builtin_amdgcn_s_barrier();
        }
    }

    const int r0 = bm * 128 + wr * 64, c0 = bn * 128 + wc * 32;
    const bool vpart = (EPI == 3) && (c0 >= 2048);   // wave-uniform (c0 32-aligned)
#pragma unroll
    for (int m = 0; m < 4; m++)
#pragma unroll
        for (int n = 0; n < 2; n++) {
            if (vpart) {
                int cc = c0 + n * 16 + (l & 15);
                int rrb = r0 + m * 16 + (l >> 4) * 4;
                ushort4 pk;
                pk.x = f2bf(acc[m][n][0]);
                pk.y = f2bf(acc[m][n][1]);
                pk.z = f2bf(acc[m][n][2]);
                pk.w = f2bf(acc[m][n][3]);
                *(ushort4*)(vout + (size_t)(cc - 2048) * 4096 + rrb) = pk;
            } else {
#pragma unroll
                for (int r = 0; r < 4; r++) {
                    int rr = r0 + m * 16 + (l >> 4) * 4 + r;
                    int cc = c0 + n * 16 + (l & 15);
                    float v = acc[m][n][r];
                    if (EPI == 1) {
                        ((unsigned short*)outp)[(size_t)rr * Nn + cc] = f2bf(gelu_tanh(v));
                    } else {
                        float sc = (cc < 1024) ? 0.180336880f : 1.0f;   // 0.125*log2(e)
                        ((unsigned short*)outp)[(size_t)rr * Nn + cc] = f2bf(v * sc);
                    }
                }
            }
        }
}

// ---- big GEMM (w1): 256x256 tile, BK=64, 8 waves (2M x 4N), 512 threads ----
template<int EPI>
__global__ __launch_bounds__(512) void gemm256(const unsigned short* __restrict__ A,
                                               const unsigned short* __restrict__ Bt,
                                               void* __restrict__ outp,
                                               unsigned short* __restrict__ vout,
                                               int M, int Nn, int K) {
    __shared__ __align__(16) unsigned short lds[2][4][8192];
    const int t = threadIdx.x, l = t & 63, w = t >> 6;
    const int wr = w >> 2, wc = w & 3;
    const int nbn = Nn >> 8;
    const int bid = blockIdx.x, nwg = gridDim.x, cpx = nwg >> 3;
    const int swz = (bid & 7) * cpx + (bid >> 3);
    const int bm = swz / nbn, bn = swz % nbn;

    const int lbase = (((l & 15) * 64 + (l >> 4) * 16)) ^ (((l >> 3) & 1) << 5);

    int srow[2], scol[2];
#pragma unroll
    for (int L = 0; L < 2; L++) {
        int g = t + L * 512;
        int s = g >> 6;
        int wb = ((g & 63) * 16) ^ (((g >> 5) & 1) << 5);
        srow[L] = (s >> 1) * 16 + (wb >> 6);
        scol[L] = (s & 1) * 32 + ((wb & 63) >> 1);
    }

    const unsigned short* Asrc = A + (size_t)(bm * 256) * K;
    const unsigned short* Bsrc = Bt + (size_t)(bn * 256) * K;

    auto stage_half = [&](int j) {
        const int kt = j >> 2, slot = j & 3;
        const unsigned short* base = (slot < 2 ? Asrc : Bsrc) + (size_t)((slot & 1) * 128) * K;
#pragma unroll
        for (int L = 0; L < 2; L++)
            load_lds16(base + (size_t)srow[L] * K + kt * 64 + scol[L],
                       &lds[kt & 1][slot][(t + L * 512) * 8]);
    };

    f32x4 acc[8][4];
#pragma unroll
    for (int m = 0; m < 8; m++)
#pragma unroll
        for (int n = 0; n < 4; n++) acc[m][n] = {0.f, 0.f, 0.f, 0.f};

    const int nkt = K >> 6;
    stage_half(0); stage_half(1); stage_half(2); stage_half(3);

    for (int kt = 0; kt < nkt; kt++) {
        wait_vm_lgkm0<0>();
        const char* Abase = (const char*)&lds[kt & 1][wr][0];
        const char* Bbase = (const char*)&lds[kt & 1][2 + (wc >> 1)][0];
        bf16x8 bfr[4][2];
#pragma unroll
        for (int q = 0; q < 4; q++) {
            if (q == 0) {
#pragma unroll
                for (int n = 0; n < 4; n++)
#pragma unroll
                    for (int ks = 0; ks < 2; ks++)
                        bfr[n][ks] = *(const bf16x8*)(Bbase + ((((wc & 1) * 4 + n) * 2 + ks) * 1024 + lbase));
            }
            bf16x8 af[2][2];
#pragma unroll
            for (int mi = 0; mi < 2; mi++)
#pragma unroll
                for (int ks = 0; ks < 2; ks++)
                    af[mi][ks] = *(const bf16x8*)(Abase + (((q * 2 + mi) * 2 + ks) * 1024 + lbase));
            if (kt + 1 < nkt && q < 2) {
                stage_half((kt + 1) * 4 + 2 * q);
                stage_half((kt + 1) * 4 + 2 * q + 1);
            }
            __builtin_amdgcn_s_barrier();
            __builtin_amdgcn_s_setprio(1);
#pragma unroll
            for (int mi = 0; mi < 2; mi++)
#pragma unroll
                for (int n = 0; n < 4; n++) {
                    acc[q * 2 + mi][n] = __builtin_amdgcn_mfma_f32_16x16x32_bf16(af[mi][0], bfr[n][0], acc[q * 2 + mi][n], 0, 0, 0);
                    acc[q * 2 + mi][n] = __builtin_amdgcn_mfma_f32_16x16x32_bf16(af[mi][1], bfr[n][1], acc[q * 2 + mi][n], 0, 0, 0);
                }
            __builtin_amdgcn_s_setprio(0);
            __builtin_amdgcn_s_barrier();
        }
    }

    const int r0 = bm * 256 + wr * 128, c0 = bn * 256 + wc * 64;
    const bool vpart = (EPI == 3) && (c0 >= 2048);
#pragma unroll
    for (int m = 0; m < 8; m++)
#pragma unroll
        for (int n = 0; n < 4; n++) {
            if (vpart) {
                int cc = c0 + n * 16 + (l & 15);
                int rrb = r0 + m * 16 + (l >> 4) * 4;
                ushort4 pk;
                pk.x = f2bf(acc[m][n][0]);
                pk.y = f2bf(acc[m][n][1]);
                pk.z = f2bf(acc[m][n][2]);
                pk.w = f2bf(acc[m][n][3]);
                *(ushort4*)(vout + (size_t)(cc - 2048) * 4096 + rrb) = pk;
            } else {
#pragma unroll
                for (int r = 0; r < 4; r++) {
                    int rr = r0 + m * 16 + (l >> 4) * 4 + r;
                    int cc = c0 + n * 16 + (l & 15);
                    float v = acc[m][n][r];
                    if (EPI == 1) {
                        ((unsigned short*)outp)[(size_t)rr * Nn + cc] = f2bf(gelu_tanh(v));
                    } else {
                        float sc = (cc < 1024) ? 0.180336880f : 1.0f;   // 0.125*log2(e)
                        ((unsigned short*)outp)[(size_t)rr * Nn + cc] = f2bf(v * sc);
                    }
                }
            }
        }
}

// ---- flash attention, swapped-operand 32x32, no-max exp2 softmax (round-12 best) ----
// KVBLK=128: 4-buffer LDS, one drain+barrier per TWO 64-key tiles.
__global__ __launch_bounds__(256) void attn_kernel(const unsigned short* __restrict__ qkv,
                                                   const unsigned short* __restrict__ vT,
                                                   unsigned short* __restrict__ o) {
    __shared__ __align__(16) unsigned short Kl[4][4096];
    __shared__ __align__(16) unsigned short Vl[4][4096];
    const int t = threadIdx.x, l = t & 63, w = t >> 6;
    const int h = blockIdx.y;
    const int qrow = blockIdx.x * 128 + w * 32 + (l & 31);

    bf16x8 qf[4];
    {
        const unsigned short* qp = qkv + (size_t)qrow * 3072 + h * 64 + ((l >> 5) * 8);
#pragma unroll
        for (int c = 0; c < 4; c++) qf[c] = *(const bf16x8*)(qp + 16 * c);
    }
    const unsigned short* kb = qkv + 1024 + h * 64;
    const unsigned short* vb = vT + (size_t)h * 64 * 4096;

    int off8[4];
#pragma unroll
    for (int c = 0; c < 4; c++)
        off8[c] = (l & 31) * 64 + ((((l >> 5) + 2 * c) ^ (l & 7)) * 8);
    int kst[2], vst[2];
#pragma unroll
    for (int p = 0; p < 2; p++) {
        int c = t + 256 * p;
        int r = c >> 3, b = c & 7;
        kst[p] = r * 3072 + ((b ^ (r & 7)) * 8);
        vst[p] = r * 4096 + ((b ^ (r & 7)) * 8);
    }

    float lrun = 0.f;
    const f32x16 z16 = {0.f, 0.f, 0.f, 0.f, 0.f, 0.f, 0.f, 0.f,
                        0.f, 0.f, 0.f, 0.f, 0.f, 0.f, 0.f, 0.f};
    f32x16 accO[2];
#pragma unroll
    for (int dt = 0; dt < 2; dt++) accO[dt] = z16;

    auto stage = [&](int tile) {
        const int buf = tile & 3;
#pragma unroll
        for (int p = 0; p < 2; p++)
            load_lds16(kb + (size_t)tile * 64 * 3072 + kst[p], &Kl[buf][(t + 256 * p) * 8]);
#pragma unroll
        for (int p = 0; p < 2; p++)
            load_lds16(vb + tile * 64 + vst[p], &Vl[buf][(t + 256 * p) * 8]);
    };

    auto compute = [&](int kt) {
        const int cur = kt & 3;
        f32x16 s[2];
        __builtin_amdgcn_s_setprio(1);
#pragma unroll
        for (int st = 0; st < 2; st++) {
            bf16x8 kf0 = *(const bf16x8*)&Kl[cur][st * 2048 + off8[0]];
            s[st] = __builtin_amdgcn_mfma_f32_32x32x16_bf16(kf0, qf[0], z16, 0, 0, 0);
#pragma unroll
            for (int c = 1; c < 4; c++) {
                bf16x8 kf = *(const bf16x8*)&Kl[cur][st * 2048 + off8[c]];
                s[st] = __builtin_amdgcn_mfma_f32_32x32x16_bf16(kf, qf[c], s[st], 0, 0, 0);
            }
        }
        __builtin_amdgcn_s_setprio(0);

        float rs = 0.f;
#pragma unroll
        for (int st = 0; st < 2; st++)
#pragma unroll
            for (int i = 0; i < 16; i++) {
                float p = __builtin_amdgcn_exp2f(s[st][i]);
                s[st][i] = p;
                rs += p;
            }
        lrun += rs;

#pragma unroll
        for (int kc = 0; kc < 4; kc++) {
            const int base = 8 * (kc & 1);
            const f32x16& S = s[kc >> 1];
            unsigned w0 = cvtpk(S[base + 0], S[base + 1]);
            unsigned w1 = cvtpk(S[base + 2], S[base + 3]);
            unsigned w2 = cvtpk(S[base + 4], S[base + 5]);
            unsigned w3 = cvtpk(S[base + 6], S[base + 7]);
            asm("v_permlane32_swap_b32 %0, %1" : "+v"(w0), "+v"(w2));
            asm("v_permlane32_swap_b32 %0, %1" : "+v"(w1), "+v"(w3));
            union { unsigned u[4]; bf16x8 v; } pf;
            pf.u[0] = w0; pf.u[1] = w1; pf.u[2] = w2; pf.u[3] = w3;
            __builtin_amdgcn_s_setprio(1);
#pragma unroll
            for (int dt = 0; dt < 2; dt++) {
                bf16x8 vf = *(const bf16x8*)&Vl[cur][dt * 2048 + off8[kc]];
                accO[dt] = __builtin_amdgcn_mfma_f32_32x32x16_bf16(vf, pf.v, accO[dt], 0, 0, 0);
            }
            __builtin_amdgcn_s_setprio(0);
        }
    };

    stage(0); stage(1);
    for (int kt = 0; kt < 64; kt += 2) {
        wait_vm_lgkm0<0>();
        if (kt + 2 < 64) { stage(kt + 2); stage(kt + 3); }
        compute(kt);
        compute(kt + 1);
    }

    lrun += __shfl_xor(lrun, 32, 64);
    float inv = 1.0f / lrun;
    unsigned short* ob = o + (size_t)qrow * CH + h * 64 + 4 * (l >> 5);
#pragma unroll
    for (int dt = 0; dt < 2; dt++)
#pragma unroll
        for (int qd = 0; qd < 4; qd++) {
            ushort4 pk;
            pk.x = f2bf(accO[dt][qd * 4 + 0] * inv);
            pk.y = f2bf(accO[dt][qd * 4 + 1] * inv);
            pk.z = f2bf(accO[dt][qd * 4 + 2] * inv);
            pk.w = f2bf(accO[dt][qd * 4 + 3] * inv);
            *(ushort4*)(ob + dt * 32 + qd * 8) = pk;
        }
}

extern "C" void kernel_launch(void* const* d_in, const int* in_sizes, int n_in,
                              void* d_out, int out_size, void* d_ws, size_t ws_size,
                              hipStream_t stream) {
    const float* x     = (const float*)d_in[0];
    const float* g1    = (const float*)d_in[1];
    const float* g2    = (const float*)d_in[2];
    const float* w_qkv = (const float*)d_in[3];
    const float* w_o   = (const float*)d_in[4];
    const float* w1    = (const float*)d_in[5];
    const float* w2    = (const float*)d_in[6];

    char* ws = (char*)d_ws;
    unsigned short* wqkvT = (unsigned short*)(ws);              // [3072][1024] bf16
    unsigned short* woT   = (unsigned short*)(ws + 6291456);    // [1024][1024]
    unsigned short* w1T   = (unsigned short*)(ws + 8388608);    // [4096][1024]
    unsigned short* w2T   = (unsigned short*)(ws + 16777216);   // [1024][4096]
    unsigned short* hbuf  = (unsigned short*)(ws + 25165824);   // [4096][1024]
    unsigned short* qkv   = (unsigned short*)(ws + 33554432);   // [4096][3072] (v-part unused)
    unsigned short* obuf  = (unsigned short*)(ws + 58720256);   // [4096][1024]
    float*          x2    = (float*)(ws + 67108864);            // [4096][1024] f32
    unsigned short* abuf  = (unsigned short*)(ws + 83886080);   // [4096][4096]
    unsigned short* vTb   = (unsigned short*)(ws + 83886080);   // [1024][4096] (aliases abuf; dead before w1 GEMM)

    dim3 b256(256), b512(512);
    wT_kernel<<<dim3(CH / 32, 3 * CH / 32), b256, 0, stream>>>(w_qkv, wqkvT, CH, 3 * CH);
    wT_kernel<<<dim3(CH / 32, CH / 32),     b256, 0, stream>>>(w_o,   woT,   CH, CH);
    wT_kernel<<<dim3(CH / 32, FF / 32),     b256, 0, stream>>>(w1,    w1T,   CH, FF);
    wT_kernel<<<dim3(FF / 32, CH / 32),     b256, 0, stream>>>(w2,    w2T,   FF, CH);

    rms_kernel<<<TOK, b256, 0, stream>>>(x, g1, hbuf);
    // qkv: 128^2 8-wave phase-interleaved GEMM (768 blocks); q-scale + fused V-transpose
    gemm128<3><<<(TOK / 128) * (3 * CH / 128), b512, 0, stream>>>(hbuf, wqkvT, qkv, vTb, TOK, 3 * CH, CH);
    attn_kernel<<<dim3(TOK / 128, NH), b256, 0, stream>>>(qkv, vTb, obuf);
    gemm_bt<64, 64, 2><<<(TOK / 64) * (CH / 64), b256, 0, stream>>>(obuf, woT, x2, x, TOK, CH, CH);
    rms_kernel<<<TOK, b256, 0, stream>>>(x2, g2, hbuf);
    // w1: 256^2 phase-interleaved GEMM with gelu epilogue (256 blocks, 1/CU)
    gemm256<1><<<(TOK / 256) * (FF / 256), b512, 0, stream>>>(hbuf, w1T, abuf, nullptr, TOK, FF, CH);
    gemm_bt<64, 64, 2><<<(TOK / 64) * (CH / 64), b256, 0, stream>>>(abuf, w2T, (float*)d_out, x2, TOK, CH, FF);
}